// Round 16
// baseline (138.317 us; speedup 1.0000x reference)
//
#include <hip/hip_runtime.h>

// QuantumGateAttention — reduced to standard MHA with transformed Wq'
// (rotation-blend + 1/sqrt(dk) + log2(e) folded). bf16 MFMA, fp32 accum.
// v15: attn re-tiled for concurrency — 64 q/block, KVT=64, LDS 40KB ->
// 4 blocks/CU (32 waves/CU). GLL16 staging (pre-swizzled source, linear
// dest), two distinct dbuf objects + 2x unroll (no vmcnt before ds_reads),
// per-qg SHARED P region (kg pair writes disjoint 64B chunk halves).

typedef __bf16 bf16;
typedef __attribute__((ext_vector_type(8))) bf16 bf16x8;
typedef __attribute__((ext_vector_type(4))) bf16 bf16x4;
typedef __attribute__((ext_vector_type(2))) bf16 bf16x2;
typedef __attribute__((ext_vector_type(4))) float f32x4;
typedef unsigned int u32;

#define D_MODEL 1024
#define NH 16
#define DKH 64
#define SEQ 2048

#define GLL16(g, l) __builtin_amdgcn_global_load_lds(                      \
    (const __attribute__((address_space(1))) void*)(g),                    \
    (__attribute__((address_space(3))) void*)(l), 16, 0, 0)

static __device__ __forceinline__ f32x4 mfma16(bf16x8 a, bf16x8 b, f32x4 c) {
  return __builtin_amdgcn_mfma_f32_16x16x32_bf16(a, b, c, 0, 0, 0);
}

static __device__ __forceinline__ u32 pk2(float a, float b) {
  bf16x2 v; v[0] = (bf16)a; v[1] = (bf16)b;
  return __builtin_bit_cast(u32, v);
}

static __device__ __forceinline__ float fexp2(float x) {
#if __has_builtin(__builtin_amdgcn_exp2f)
  return __builtin_amdgcn_exp2f(x);
#else
  return exp2f(x);
#endif
}

// scale = 1/sqrt(dk) * log2(e)
#define CQK 0.1803368801111244f
// static softmax shift (log2 units)
#define MSHIFT 12.0f

// ---------------------------------------------------------------------------
// prep: id<4096 -> weights (wz=id>>10: 0 Wq'-transform, 1..3 cvt Wk/Wv/Wo);
//       id>=4096 -> input cvt (iz: 0 q, 1 k, 2 v)
// ---------------------------------------------------------------------------
__global__ __launch_bounds__(256) void prep(const float* __restrict__ query,
                                            const float* __restrict__ key,
                                            const float* __restrict__ value,
                                            const float* __restrict__ Wq,
                                            const float* __restrict__ bq,
                                            const float* __restrict__ Wk,
                                            const float* __restrict__ Wv,
                                            const float* __restrict__ Wo,
                                            const float* __restrict__ gate,
                                            const float* __restrict__ theta,
                                            bf16* __restrict__ Xq,
                                            bf16* __restrict__ Xk,
                                            bf16* __restrict__ Xv,
                                            bf16* __restrict__ Wqp,
                                            bf16* __restrict__ Wkp,
                                            bf16* __restrict__ Wvp,
                                            bf16* __restrict__ Wop,
                                            float* __restrict__ bqp) {
  const int id = blockIdx.x;
  const int tid = threadIdx.x;
  if (id >= 4096) {
    const int rem = id - 4096;
    const int iz = rem >> 12;
    const int ib = rem & 4095;
    const float* s = (iz == 0) ? query : (iz == 1) ? key : value;
    bf16* d = (iz == 0) ? Xq : (iz == 1) ? Xk : Xv;
    const size_t i = (size_t)(ib * 256 + tid) * 4;
    float4 w = *(const float4*)(s + i);
    bf16x4 o; o[0] = (bf16)w.x; o[1] = (bf16)w.y; o[2] = (bf16)w.z; o[3] = (bf16)w.w;
    *(bf16x4*)(d + i) = o;
    return;
  }
  const int wz = id >> 10, wb = id & 1023;
  if (wz != 0) {
    const float* s = (wz == 1) ? Wk : (wz == 2) ? Wv : Wo;
    bf16* dd = (wz == 1) ? Wkp : (wz == 2) ? Wvp : Wop;
    const size_t i = (size_t)(wb * 256 + tid) * 4;
    float4 v = *(const float4*)(s + i);
    bf16x4 o4; o4[0] = (bf16)v.x; o4[1] = (bf16)v.y; o4[2] = (bf16)v.z; o4[3] = (bf16)v.w;
    *(bf16x4*)(dd + i) = o4;
    return;
  }
  __shared__ float red[4];
  float ssum = 0.f;
  for (int i = tid; i < D_MODEL; i += 256) ssum += gate[i];
#pragma unroll
  for (int off = 32; off > 0; off >>= 1) ssum += __shfl_down(ssum, off);
  if ((tid & 63) == 0) red[tid >> 6] = ssum;
  __syncthreads();
  const float g = 1.f / (1.f + __expf(-(red[0] + red[1] + red[2] + red[3]) / 1024.f));

  const int t = wb * 256 + tid;
  const int r = t >> 8;
  const int c0 = (t & 255) * 4;
  const int d = r & 63, h = r >> 6;
  float4 w = *(const float4*)(Wq + (size_t)r * D_MODEL + c0);
  float4 o;
  if (d == 0) {
    const float a = (g * cosf(theta[h]) + (1.f - g)) * CQK;
    const float bb = (g * sinf(theta[h])) * CQK;
    float4 w2 = *(const float4*)(Wq + (size_t)(r + 1) * D_MODEL + c0);
    o.x = a * w.x - bb * w2.x; o.y = a * w.y - bb * w2.y;
    o.z = a * w.z - bb * w2.z; o.w = a * w.w - bb * w2.w;
    if (c0 == 0) bqp[r] = a * bq[r] - bb * bq[r + 1];
  } else if (d == 1) {
    const float a = (g * cosf(theta[h]) + (1.f - g)) * CQK;
    const float bb = (g * sinf(theta[h])) * CQK;
    float4 w2 = *(const float4*)(Wq + (size_t)(r - 1) * D_MODEL + c0);
    o.x = bb * w2.x + a * w.x; o.y = bb * w2.y + a * w.y;
    o.z = bb * w2.z + a * w.z; o.w = bb * w2.w + a * w.w;
    if (c0 == 0) bqp[r] = bb * bq[r - 1] + a * bq[r];
  } else {
    o.x = CQK * w.x; o.y = CQK * w.y;
    o.z = CQK * w.z; o.w = CQK * w.w;
    if (c0 == 0) bqp[r] = CQK * bq[r];
  }
  bf16x4 ov; ov[0] = (bf16)o.x; ov[1] = (bf16)o.y; ov[2] = (bf16)o.z; ov[3] = (bf16)o.w;
  *(bf16x4*)(Wqp + (size_t)r * D_MODEL + c0) = ov;
}

// ---------------------------------------------------------------------------
// GEMM main loop: C(128x128) = A * Bt^T, BK=64, GLL16 staging with oct^row
// swizzle (pre-swizzled global source, linear LDS dest).
// ---------------------------------------------------------------------------
static __device__ __forceinline__ void gemm_bt_main(const bf16* __restrict__ A,
                                                    const bf16* __restrict__ Bt,
                                                    int tm, int tn, int K,
                                                    f32x4 acc[4][4]) {
  __shared__ bf16 lA[8192];  // [128][64], chunk oct ^= (row&7)
  __shared__ bf16 lB[8192];
  const int tid = threadIdx.x;
  const int lane = tid & 63, wv = tid >> 6;
  const int wm = wv >> 1, wn = wv & 1;
  const int l16 = lane & 15, lg = lane >> 4;

#pragma unroll
  for (int i = 0; i < 4; ++i)
#pragma unroll
    for (int j = 0; j < 4; ++j) acc[i][j] = (f32x4){0.f, 0.f, 0.f, 0.f};

  int offA[4][2], offB[4][2];
#pragma unroll
  for (int f = 0; f < 4; ++f)
#pragma unroll
    for (int kc = 0; kc < 2; ++kc) {
      const int m = wm * 64 + f * 16 + l16;
      offA[f][kc] = m * 64 + (((kc * 4 + lg) ^ (m & 7)) << 3);
      const int n = wn * 64 + f * 16 + l16;
      offB[f][kc] = n * 64 + (((kc * 4 + lg) ^ (n & 7)) << 3);
    }

  const int rowb = tid >> 3, oct = tid & 7;
  const int soct = oct ^ (rowb & 7);
  const bf16* gA[4];
  const bf16* gB[4];
#pragma unroll
  for (int rd = 0; rd < 4; ++rd) {
    gA[rd] = A + (size_t)(tm + rd * 32 + rowb) * K + soct * 8;
    gB[rd] = Bt + (size_t)(tn + rd * 32 + rowb) * K + soct * 8;
  }

  for (int kt = 0; kt < K; kt += 64) {
    __syncthreads();
#pragma unroll
    for (int rd = 0; rd < 4; ++rd) {
      GLL16(gA[rd] + kt, &lA[rd * 2048 + wv * 512]);
      GLL16(gB[rd] + kt, &lB[rd * 2048 + wv * 512]);
    }
    __syncthreads();
#pragma unroll
    for (int kc = 0; kc < 2; ++kc) {
      bf16x8 af[4], bv[4];
#pragma unroll
      for (int f = 0; f < 4; ++f) {
        af[f] = *(const bf16x8*)&lA[offA[f][kc]];
        bv[f] = *(const bf16x8*)&lB[offB[f][kc]];
      }
#pragma unroll
      for (int i = 0; i < 4; ++i)
#pragma unroll
        for (int j = 0; j < 4; ++j)
          acc[i][j] = mfma16(af[i], bv[j], acc[i][j]);
    }
  }
}

// QKV projections (1D grid 768, XCD-swizzled): z=0 Q', z=1 K -> [B,H,S,64];
// z=2 V -> Vt [B,H,64,S].
__global__ __launch_bounds__(256) void gemm_qkv(
    const bf16* __restrict__ Xq, const bf16* __restrict__ Xk, const bf16* __restrict__ Xv,
    const bf16* __restrict__ Wq, const bf16* __restrict__ Wk, const bf16* __restrict__ Wv,
    const float* __restrict__ bqp, const float* __restrict__ bk, const float* __restrict__ bv,
    bf16* __restrict__ Qp, bf16* __restrict__ Kp, bf16* __restrict__ Vt) {
  const int wgp = (blockIdx.x & 7) * 96 + (blockIdx.x >> 3);  // 768 = 8*96
  const int z = wgp >> 8;
  const int rem = wgp & 255;
  const int tm = (rem >> 3) * 128, tn = (rem & 7) * 128;
  const bf16* A = (z == 0) ? Xq : (z == 1) ? Xk : Xv;
  const bf16* Bt = (z == 0) ? Wq : (z == 1) ? Wk : Wv;
  const float* bias = (z == 0) ? bqp : (z == 1) ? bk : bv;
  f32x4 acc[4][4];
  gemm_bt_main(A, Bt, tm, tn, D_MODEL, acc);
  const int lane = threadIdx.x & 63, wv = threadIdx.x >> 6;
  const int wm = wv >> 1, wn = wv & 1, l16 = lane & 15, lg = lane >> 4;
  if (z < 2) {
    bf16* C = (z == 0) ? Qp : Kp;
#pragma unroll
    for (int i = 0; i < 4; ++i) {
      const int m0 = tm + wm * 64 + i * 16 + lg * 4;
#pragma unroll
      for (int j = 0; j < 4; ++j) {
        const int n = tn + wn * 64 + j * 16 + l16;
        const float bb = bias[n];
        const int h = n >> 6, d = n & 63;
#pragma unroll
        for (int r = 0; r < 4; ++r) {
          const int m = m0 + r;
          const int b = m >> 11, s = m & 2047;
          C[((size_t)(b * NH + h) * SEQ + s) * DKH + d] = (bf16)(acc[i][j][r] + bb);
        }
      }
    }
  } else {
#pragma unroll
    for (int i = 0; i < 4; ++i) {
      const int m0 = tm + wm * 64 + i * 16 + lg * 4;
      const int b = m0 >> 11, s0 = m0 & 2047;
#pragma unroll
      for (int j = 0; j < 4; ++j) {
        const int n = tn + wn * 64 + j * 16 + l16;
        const float bb = bias[n];
        const int h = n >> 6, d = n & 63;
        bf16x4 ov;
#pragma unroll
        for (int r = 0; r < 4; ++r) ov[r] = (bf16)(acc[i][j][r] + bb);
        *(bf16x4*)&Vt[((size_t)(b * NH + h) * DKH + d) * SEQ + s0] = ov;
      }
    }
  }
}

// final projection (1D grid 256, XCD-swizzled): d_out = O @ Wo^T + bo, fp32
__global__ __launch_bounds__(256) void gemm_out_k(const bf16* __restrict__ A,
                                                  const bf16* __restrict__ Bt,
                                                  const float* __restrict__ bias,
                                                  float* __restrict__ C) {
  const int wgp = (blockIdx.x & 7) * 32 + (blockIdx.x >> 3);  // 256 = 8*32
  const int tm = (wgp >> 3) * 128, tn = (wgp & 7) * 128;
  f32x4 acc[4][4];
  gemm_bt_main(A, Bt, tm, tn, D_MODEL, acc);
  const int lane = threadIdx.x & 63, wv = threadIdx.x >> 6;
  const int wm = wv >> 1, wn = wv & 1, l16 = lane & 15, lg = lane >> 4;
#pragma unroll
  for (int i = 0; i < 4; ++i) {
    const int m0 = tm + wm * 64 + i * 16 + lg * 4;
#pragma unroll
    for (int j = 0; j < 4; ++j) {
      const int n = tn + wn * 64 + j * 16 + l16;
      const float bb = bias[n];
#pragma unroll
      for (int r = 0; r < 4; ++r)
        C[(size_t)(m0 + r) * D_MODEL + n] = acc[i][j][r] + bb;
    }
  }
}

// ---------------------------------------------------------------------------
// Flash attention v15: 64 q/block, KVT=64, 8 waves = 4 qg x 2 kg, grid 1024.
// LDS 40KB -> 4 blocks/CU (32 waves/CU). GLL16 staging, distinct dbuf
// objects + 2x unroll. P shared per qg wave-pair: [16 q][64 k] @128B rows;
// kg=0 owns chunks 0-3, kg=1 chunks 4-7 (disjoint, bank-balanced).
// Static-shift softmax; l via ones-MFMA; LDS combine epilogue.
// ---------------------------------------------------------------------------
__global__ __launch_bounds__(512, 8) void attn_kernel(const bf16* __restrict__ Qp,
                                                      const bf16* __restrict__ Kp,
                                                      const bf16* __restrict__ Vt,
                                                      bf16* __restrict__ Op) {
  __shared__ __align__(16) bf16 lK0[4096];  // [64 k][64 d], content oct^(kr&7)
  __shared__ __align__(16) bf16 lV0[4096];  // [64 d][64 k], content c^(d&7)
  __shared__ __align__(16) bf16 lK1[4096];
  __shared__ __align__(16) bf16 lV1[4096];
  __shared__ __align__(16) bf16 lP[4096];   // 4 qg x [16 q][64 k]

  const int tid = threadIdx.x;
  const int lane = tid & 63, w = tid >> 6;
  const int l16 = lane & 15, lg = lane >> 4;
  const int qg = w >> 1, kg = w & 1;
  const int wgp = (blockIdx.x & 7) * 128 + (blockIdx.x >> 3);  // 1024 = 8*128
  const int bh = wgp >> 5;
  const int b = bh >> 4, h = bh & 15;
  const int q0 = (wgp & 31) * 64;
  const int qw0 = q0 + qg * 16;
  const size_t kvb = (size_t)bh * SEQ * DKH;

  bf16x8 aq[2];
#pragma unroll
  for (int kc = 0; kc < 2; ++kc)
    aq[kc] = *(const bf16x8*)&Qp[kvb + (size_t)(qw0 + l16) * DKH + kc * 32 + lg * 8];

  f32x4 o[4];
#pragma unroll
  for (int dt = 0; dt < 4; ++dt) o[dt] = (f32x4){0.f, 0.f, 0.f, 0.f};
  f32x4 lacc = (f32x4){0.f, 0.f, 0.f, 0.f};

  bf16x8 ones;
#pragma unroll
  for (int j = 0; j < 8; ++j) ones[j] = (bf16)1.0f;

  // staging (pre-swizzled source, linear dest tid*16B):
  const int kr = tid >> 3, oct = tid & 7;       // K: row kr in [0,64), chunk oct
  const bf16* gKs = Kp + kvb + (size_t)kr * DKH + (oct ^ (kr & 7)) * 8;
  const bf16* gVs = Vt + kvb + (size_t)kr * SEQ + (oct ^ (kr & 7)) * 8;  // V: row d=kr
  // P: per-qg region [16 q][64 k] @ 128B rows; this wave owns chunks kg*4..kg*4+3
  bf16* lPq = &lP[qg * 1024];
  int pwr[2];
#pragma unroll
  for (int fn = 0; fn < 2; ++fn)
    pwr[fn] = l16 * 64 + (((kg * 4 + fn * 2 + (lg >> 1)) ^ (l16 & 7)) << 3) +
              ((lg & 1) << 2);
  const int prd = l16 * 64 + (((kg * 4 + lg) ^ (l16 & 7)) << 3);

  auto stageTile = [&](bf16* dK, bf16* dV, int t) {
    const size_t ko = (size_t)t * 64 * DKH;
    const int vo = t * 64;
    GLL16(gKs + ko, dK + tid * 8);
    GLL16(gVs + vo, dV + tid * 8);
  };

  auto computeTile = [&](const bf16* K, const bf16* V) {
    // S^T: st[fn][r] = S[q=qw0+l16][k = kg*32 + fn*16 + lg*4 + r] (log2 units)
    f32x4 st[2];
    __builtin_amdgcn_s_setprio(1);
#pragma unroll
    for (int fn = 0; fn < 2; ++fn) {
      const int row = kg * 32 + fn * 16 + l16;
      bf16x8 ka = *(const bf16x8*)&K[row * 64 + ((lg ^ (row & 7)) << 3)];
      bf16x8 kb = *(const bf16x8*)&K[row * 64 + (((4 + lg) ^ (row & 7)) << 3)];
      f32x4 tt = (f32x4){0.f, 0.f, 0.f, 0.f};
      tt = mfma16(ka, aq[0], tt);
      tt = mfma16(kb, aq[1], tt);
      st[fn] = tt;
    }
    __builtin_amdgcn_s_setprio(0);

    // P = exp2(S - MSHIFT) -> shared per-qg LDS (A-frag layout, own chunks)
#pragma unroll
    for (int fn = 0; fn < 2; ++fn) {
      uint2 pw;
      pw.x = pk2(fexp2(st[fn][0] - MSHIFT), fexp2(st[fn][1] - MSHIFT));
      pw.y = pk2(fexp2(st[fn][2] - MSHIFT), fexp2(st[fn][3] - MSHIFT));
      *(uint2*)&lPq[pwr[fn]] = pw;
    }
    bf16x8 pa = *(const bf16x8*)&lPq[prd];

    __builtin_amdgcn_s_setprio(1);
    lacc = mfma16(pa, ones, lacc);
#pragma unroll
    for (int dt = 0; dt < 4; ++dt) {
      const int n = dt * 16 + l16;
      bf16x8 vv = *(const bf16x8*)&V[n * 64 + (((kg * 4 + lg) ^ (n & 7)) << 3)];
      o[dt] = mfma16(pa, vv, o[dt]);
    }
    __builtin_amdgcn_s_setprio(0);
  };

  stageTile(lK0, lV0, 0);
  __syncthreads();

  const int NT = SEQ / 64;  // 32 (even)
  for (int t = 0; t < NT; t += 2) {
    if (t + 1 < NT) stageTile(lK1, lV1, t + 1);
    computeTile(lK0, lV0);
    __syncthreads();
    if (t + 2 < NT) stageTile(lK0, lV0, t + 2);
    computeTile(lK1, lV1);
    __syncthreads();
  }

  // ---- combine the two k-halves (partials additive: static shift) ----
  // qg0->lK0, qg1->lV0, qg2->lK1, qg3->lV1 (all dead); l in lP.
  float* cmb = (qg == 0) ? (float*)lK0 : (qg == 1) ? (float*)lV0
             : (qg == 2) ? (float*)lK1 : (float*)lV1;
  float* cl = (float*)lP;
  if (kg == 1) {
#pragma unroll
    for (int dt = 0; dt < 4; ++dt)
      *(f32x4*)&cmb[(dt * 16 + l16) * 16 + lg * 4] = o[dt];
    if (l16 == 0) {
#pragma unroll
      for (int r = 0; r < 4; ++r)
        cl[qg * 16 + lg * 4 + r] = lacc[r];
    }
  }
  __syncthreads();
  if (kg == 0) {
#pragma unroll
    for (int dt = 0; dt < 4; ++dt) {
      f32x4 p = *(const f32x4*)&cmb[(dt * 16 + l16) * 16 + lg * 4];
      o[dt][0] += p[0]; o[dt][1] += p[1];
      o[dt][2] += p[2]; o[dt][3] += p[3];
    }
    float linv[4];
#pragma unroll
    for (int r = 0; r < 4; ++r)
      linv[r] = 1.f / (lacc[r] + cl[qg * 16 + lg * 4 + r]);
#pragma unroll
    for (int r = 0; r < 4; ++r) {
      const int q = qw0 + lg * 4 + r;
#pragma unroll
      for (int dt = 0; dt < 4; ++dt) {
        const int d = dt * 16 + l16;
        Op[((size_t)(b * SEQ + q)) * D_MODEL + h * DKH + d] =
            (bf16)(o[dt][r] * linv[r]);
      }
    }
  }
}

// ---------------------------------------------------------------------------
extern "C" void kernel_launch(void* const* d_in, const int* in_sizes, int n_in,
                              void* d_out, int out_size, void* d_ws, size_t ws_size,
                              hipStream_t stream) {
  (void)in_sizes; (void)n_in; (void)out_size; (void)ws_size;
  const float* query = (const float*)d_in[0];
  const float* key   = (const float*)d_in[1];
  const float* value = (const float*)d_in[2];
  const float* Wq    = (const float*)d_in[3];
  const float* bq    = (const float*)d_in[4];
  const float* Wk    = (const float*)d_in[5];
  const float* bk    = (const float*)d_in[6];
  const float* Wv    = (const float*)d_in[7];
  const float* bv    = (const float*)d_in[8];
  const float* Wo    = (const float*)d_in[9];
  const float* bo    = (const float*)d_in[10];
  const float* theta = (const float*)d_in[11];
  const float* gate  = (const float*)d_in[12];

  float* bqp = (float*)d_ws;       // 1024 floats (transformed bq)
  bf16* wb = (bf16*)((char*)d_ws + 8192);
  bf16* Xq  = wb;                  // 4096x1024 bf16
  bf16* Xk  = Xq + 4194304;
  bf16* Xv  = Xk + 4194304;
  bf16* Wqp = Xv + 4194304;        // 1024x1024 bf16 (transformed)
  bf16* Wkp = Wqp + 1048576;
  bf16* Wvp = Wkp + 1048576;
  bf16* Wop = Wvp + 1048576;
  bf16* Qp  = Wop + 1048576;       // [B,H,S,64] bf16
  bf16* Kp  = Qp + 4194304;
  bf16* Vt  = Kp + 4194304;        // [B,H,64,S] bf16 (V transposed)
  bf16* Op  = Vt + 4194304;        // [B,S,1024] bf16

  prep<<<16384, 256, 0, stream>>>(query, key, value, Wq, bq, Wk, Wv, Wo,
                                  gate, theta, Xq, Xk, Xv,
                                  Wqp, Wkp, Wvp, Wop, bqp);
  gemm_qkv<<<768, 256, 0, stream>>>(Xq, Xk, Xv, Wqp, Wkp, Wvp,
                                    bqp, bk, bv, Qp, Kp, Vt);
  attn_kernel<<<1024, 512, 0, stream>>>(Qp, Kp, Vt, Op);
  gemm_out_k<<<256, 256, 0, stream>>>(Op, Wop, bo, (float*)d_out);
}

// Round 17
// 129.069 us; speedup vs baseline: 1.0716x; 1.0716x over previous
//
#include <hip/hip_runtime.h>

// QuantumGateAttention — reduced to standard MHA with transformed Wq'
// (rotation-blend + 1/sqrt(dk) + log2(e) folded). bf16 MFMA, fp32 accum.
// v16 = v15 with __launch_bounds__(512,4): v15's (512,8) forced VGPR=32 ->
// 30MB scratch spills. LDS (40KB) still gives 4 blocks/CU = 32 waves/CU.

typedef __bf16 bf16;
typedef __attribute__((ext_vector_type(8))) bf16 bf16x8;
typedef __attribute__((ext_vector_type(4))) bf16 bf16x4;
typedef __attribute__((ext_vector_type(2))) bf16 bf16x2;
typedef __attribute__((ext_vector_type(4))) float f32x4;
typedef unsigned int u32;

#define D_MODEL 1024
#define NH 16
#define DKH 64
#define SEQ 2048

#define GLL16(g, l) __builtin_amdgcn_global_load_lds(                      \
    (const __attribute__((address_space(1))) void*)(g),                    \
    (__attribute__((address_space(3))) void*)(l), 16, 0, 0)

static __device__ __forceinline__ f32x4 mfma16(bf16x8 a, bf16x8 b, f32x4 c) {
  return __builtin_amdgcn_mfma_f32_16x16x32_bf16(a, b, c, 0, 0, 0);
}

static __device__ __forceinline__ u32 pk2(float a, float b) {
  bf16x2 v; v[0] = (bf16)a; v[1] = (bf16)b;
  return __builtin_bit_cast(u32, v);
}

static __device__ __forceinline__ float fexp2(float x) {
#if __has_builtin(__builtin_amdgcn_exp2f)
  return __builtin_amdgcn_exp2f(x);
#else
  return exp2f(x);
#endif
}

// scale = 1/sqrt(dk) * log2(e)
#define CQK 0.1803368801111244f
// static softmax shift (log2 units)
#define MSHIFT 12.0f

// ---------------------------------------------------------------------------
// prep: id<4096 -> weights (wz=id>>10: 0 Wq'-transform, 1..3 cvt Wk/Wv/Wo);
//       id>=4096 -> input cvt (iz: 0 q, 1 k, 2 v)
// ---------------------------------------------------------------------------
__global__ __launch_bounds__(256) void prep(const float* __restrict__ query,
                                            const float* __restrict__ key,
                                            const float* __restrict__ value,
                                            const float* __restrict__ Wq,
                                            const float* __restrict__ bq,
                                            const float* __restrict__ Wk,
                                            const float* __restrict__ Wv,
                                            const float* __restrict__ Wo,
                                            const float* __restrict__ gate,
                                            const float* __restrict__ theta,
                                            bf16* __restrict__ Xq,
                                            bf16* __restrict__ Xk,
                                            bf16* __restrict__ Xv,
                                            bf16* __restrict__ Wqp,
                                            bf16* __restrict__ Wkp,
                                            bf16* __restrict__ Wvp,
                                            bf16* __restrict__ Wop,
                                            float* __restrict__ bqp) {
  const int id = blockIdx.x;
  const int tid = threadIdx.x;
  if (id >= 4096) {
    const int rem = id - 4096;
    const int iz = rem >> 12;
    const int ib = rem & 4095;
    const float* s = (iz == 0) ? query : (iz == 1) ? key : value;
    bf16* d = (iz == 0) ? Xq : (iz == 1) ? Xk : Xv;
    const size_t i = (size_t)(ib * 256 + tid) * 4;
    float4 w = *(const float4*)(s + i);
    bf16x4 o; o[0] = (bf16)w.x; o[1] = (bf16)w.y; o[2] = (bf16)w.z; o[3] = (bf16)w.w;
    *(bf16x4*)(d + i) = o;
    return;
  }
  const int wz = id >> 10, wb = id & 1023;
  if (wz != 0) {
    const float* s = (wz == 1) ? Wk : (wz == 2) ? Wv : Wo;
    bf16* dd = (wz == 1) ? Wkp : (wz == 2) ? Wvp : Wop;
    const size_t i = (size_t)(wb * 256 + tid) * 4;
    float4 v = *(const float4*)(s + i);
    bf16x4 o4; o4[0] = (bf16)v.x; o4[1] = (bf16)v.y; o4[2] = (bf16)v.z; o4[3] = (bf16)v.w;
    *(bf16x4*)(dd + i) = o4;
    return;
  }
  __shared__ float red[4];
  float ssum = 0.f;
  for (int i = tid; i < D_MODEL; i += 256) ssum += gate[i];
#pragma unroll
  for (int off = 32; off > 0; off >>= 1) ssum += __shfl_down(ssum, off);
  if ((tid & 63) == 0) red[tid >> 6] = ssum;
  __syncthreads();
  const float g = 1.f / (1.f + __expf(-(red[0] + red[1] + red[2] + red[3]) / 1024.f));

  const int t = wb * 256 + tid;
  const int r = t >> 8;
  const int c0 = (t & 255) * 4;
  const int d = r & 63, h = r >> 6;
  float4 w = *(const float4*)(Wq + (size_t)r * D_MODEL + c0);
  float4 o;
  if (d == 0) {
    const float a = (g * cosf(theta[h]) + (1.f - g)) * CQK;
    const float bb = (g * sinf(theta[h])) * CQK;
    float4 w2 = *(const float4*)(Wq + (size_t)(r + 1) * D_MODEL + c0);
    o.x = a * w.x - bb * w2.x; o.y = a * w.y - bb * w2.y;
    o.z = a * w.z - bb * w2.z; o.w = a * w.w - bb * w2.w;
    if (c0 == 0) bqp[r] = a * bq[r] - bb * bq[r + 1];
  } else if (d == 1) {
    const float a = (g * cosf(theta[h]) + (1.f - g)) * CQK;
    const float bb = (g * sinf(theta[h])) * CQK;
    float4 w2 = *(const float4*)(Wq + (size_t)(r - 1) * D_MODEL + c0);
    o.x = bb * w2.x + a * w.x; o.y = bb * w2.y + a * w.y;
    o.z = bb * w2.z + a * w.z; o.w = bb * w2.w + a * w.w;
    if (c0 == 0) bqp[r] = bb * bq[r - 1] + a * bq[r];
  } else {
    o.x = CQK * w.x; o.y = CQK * w.y;
    o.z = CQK * w.z; o.w = CQK * w.w;
    if (c0 == 0) bqp[r] = CQK * bq[r];
  }
  bf16x4 ov; ov[0] = (bf16)o.x; ov[1] = (bf16)o.y; ov[2] = (bf16)o.z; ov[3] = (bf16)o.w;
  *(bf16x4*)(Wqp + (size_t)r * D_MODEL + c0) = ov;
}

// ---------------------------------------------------------------------------
// GEMM main loop: C(128x128) = A * Bt^T, BK=64, GLL16 staging with oct^row
// swizzle (pre-swizzled global source, linear LDS dest).
// ---------------------------------------------------------------------------
static __device__ __forceinline__ void gemm_bt_main(const bf16* __restrict__ A,
                                                    const bf16* __restrict__ Bt,
                                                    int tm, int tn, int K,
                                                    f32x4 acc[4][4]) {
  __shared__ bf16 lA[8192];  // [128][64], chunk oct ^= (row&7)
  __shared__ bf16 lB[8192];
  const int tid = threadIdx.x;
  const int lane = tid & 63, wv = tid >> 6;
  const int wm = wv >> 1, wn = wv & 1;
  const int l16 = lane & 15, lg = lane >> 4;

#pragma unroll
  for (int i = 0; i < 4; ++i)
#pragma unroll
    for (int j = 0; j < 4; ++j) acc[i][j] = (f32x4){0.f, 0.f, 0.f, 0.f};

  int offA[4][2], offB[4][2];
#pragma unroll
  for (int f = 0; f < 4; ++f)
#pragma unroll
    for (int kc = 0; kc < 2; ++kc) {
      const int m = wm * 64 + f * 16 + l16;
      offA[f][kc] = m * 64 + (((kc * 4 + lg) ^ (m & 7)) << 3);
      const int n = wn * 64 + f * 16 + l16;
      offB[f][kc] = n * 64 + (((kc * 4 + lg) ^ (n & 7)) << 3);
    }

  const int rowb = tid >> 3, oct = tid & 7;
  const int soct = oct ^ (rowb & 7);
  const bf16* gA[4];
  const bf16* gB[4];
#pragma unroll
  for (int rd = 0; rd < 4; ++rd) {
    gA[rd] = A + (size_t)(tm + rd * 32 + rowb) * K + soct * 8;
    gB[rd] = Bt + (size_t)(tn + rd * 32 + rowb) * K + soct * 8;
  }

  for (int kt = 0; kt < K; kt += 64) {
    __syncthreads();
#pragma unroll
    for (int rd = 0; rd < 4; ++rd) {
      GLL16(gA[rd] + kt, &lA[rd * 2048 + wv * 512]);
      GLL16(gB[rd] + kt, &lB[rd * 2048 + wv * 512]);
    }
    __syncthreads();
#pragma unroll
    for (int kc = 0; kc < 2; ++kc) {
      bf16x8 af[4], bv[4];
#pragma unroll
      for (int f = 0; f < 4; ++f) {
        af[f] = *(const bf16x8*)&lA[offA[f][kc]];
        bv[f] = *(const bf16x8*)&lB[offB[f][kc]];
      }
#pragma unroll
      for (int i = 0; i < 4; ++i)
#pragma unroll
        for (int j = 0; j < 4; ++j)
          acc[i][j] = mfma16(af[i], bv[j], acc[i][j]);
    }
  }
}

// QKV projections (1D grid 768, XCD-swizzled): z=0 Q', z=1 K -> [B,H,S,64];
// z=2 V -> Vt [B,H,64,S].
__global__ __launch_bounds__(256) void gemm_qkv(
    const bf16* __restrict__ Xq, const bf16* __restrict__ Xk, const bf16* __restrict__ Xv,
    const bf16* __restrict__ Wq, const bf16* __restrict__ Wk, const bf16* __restrict__ Wv,
    const float* __restrict__ bqp, const float* __restrict__ bk, const float* __restrict__ bv,
    bf16* __restrict__ Qp, bf16* __restrict__ Kp, bf16* __restrict__ Vt) {
  const int wgp = (blockIdx.x & 7) * 96 + (blockIdx.x >> 3);  // 768 = 8*96
  const int z = wgp >> 8;
  const int rem = wgp & 255;
  const int tm = (rem >> 3) * 128, tn = (rem & 7) * 128;
  const bf16* A = (z == 0) ? Xq : (z == 1) ? Xk : Xv;
  const bf16* Bt = (z == 0) ? Wq : (z == 1) ? Wk : Wv;
  const float* bias = (z == 0) ? bqp : (z == 1) ? bk : bv;
  f32x4 acc[4][4];
  gemm_bt_main(A, Bt, tm, tn, D_MODEL, acc);
  const int lane = threadIdx.x & 63, wv = threadIdx.x >> 6;
  const int wm = wv >> 1, wn = wv & 1, l16 = lane & 15, lg = lane >> 4;
  if (z < 2) {
    bf16* C = (z == 0) ? Qp : Kp;
#pragma unroll
    for (int i = 0; i < 4; ++i) {
      const int m0 = tm + wm * 64 + i * 16 + lg * 4;
#pragma unroll
      for (int j = 0; j < 4; ++j) {
        const int n = tn + wn * 64 + j * 16 + l16;
        const float bb = bias[n];
        const int h = n >> 6, d = n & 63;
#pragma unroll
        for (int r = 0; r < 4; ++r) {
          const int m = m0 + r;
          const int b = m >> 11, s = m & 2047;
          C[((size_t)(b * NH + h) * SEQ + s) * DKH + d] = (bf16)(acc[i][j][r] + bb);
        }
      }
    }
  } else {
#pragma unroll
    for (int i = 0; i < 4; ++i) {
      const int m0 = tm + wm * 64 + i * 16 + lg * 4;
      const int b = m0 >> 11, s0 = m0 & 2047;
#pragma unroll
      for (int j = 0; j < 4; ++j) {
        const int n = tn + wn * 64 + j * 16 + l16;
        const float bb = bias[n];
        const int h = n >> 6, d = n & 63;
        bf16x4 ov;
#pragma unroll
        for (int r = 0; r < 4; ++r) ov[r] = (bf16)(acc[i][j][r] + bb);
        *(bf16x4*)&Vt[((size_t)(b * NH + h) * DKH + d) * SEQ + s0] = ov;
      }
    }
  }
}

// final projection (1D grid 256, XCD-swizzled): d_out = O @ Wo^T + bo, fp32
__global__ __launch_bounds__(256) void gemm_out_k(const bf16* __restrict__ A,
                                                  const bf16* __restrict__ Bt,
                                                  const float* __restrict__ bias,
                                                  float* __restrict__ C) {
  const int wgp = (blockIdx.x & 7) * 32 + (blockIdx.x >> 3);  // 256 = 8*32
  const int tm = (wgp >> 3) * 128, tn = (wgp & 7) * 128;
  f32x4 acc[4][4];
  gemm_bt_main(A, Bt, tm, tn, D_MODEL, acc);
  const int lane = threadIdx.x & 63, wv = threadIdx.x >> 6;
  const int wm = wv >> 1, wn = wv & 1, l16 = lane & 15, lg = lane >> 4;
#pragma unroll
  for (int i = 0; i < 4; ++i) {
    const int m0 = tm + wm * 64 + i * 16 + lg * 4;
#pragma unroll
    for (int j = 0; j < 4; ++j) {
      const int n = tn + wn * 64 + j * 16 + l16;
      const float bb = bias[n];
#pragma unroll
      for (int r = 0; r < 4; ++r)
        C[(size_t)(m0 + r) * D_MODEL + n] = acc[i][j][r] + bb;
    }
  }
}

// ---------------------------------------------------------------------------
// Flash attention v16: 64 q/block, KVT=64, 8 waves = 4 qg x 2 kg, grid 1024.
// LDS 40KB -> 4 blocks/CU (32 waves/CU); launch_bounds (512,4) so VGPRs
// don't spill. GLL16 staging, distinct dbuf objects + 2x unroll. P shared
// per qg wave-pair: [16 q][64 k] @128B rows; kg=0 chunks 0-3, kg=1 4-7.
// Static-shift softmax; l via ones-MFMA; LDS combine epilogue.
// ---------------------------------------------------------------------------
__global__ __launch_bounds__(512, 4) void attn_kernel(const bf16* __restrict__ Qp,
                                                      const bf16* __restrict__ Kp,
                                                      const bf16* __restrict__ Vt,
                                                      bf16* __restrict__ Op) {
  __shared__ __align__(16) bf16 lK0[4096];  // [64 k][64 d], content oct^(kr&7)
  __shared__ __align__(16) bf16 lV0[4096];  // [64 d][64 k], content c^(d&7)
  __shared__ __align__(16) bf16 lK1[4096];
  __shared__ __align__(16) bf16 lV1[4096];
  __shared__ __align__(16) bf16 lP[4096];   // 4 qg x [16 q][64 k]

  const int tid = threadIdx.x;
  const int lane = tid & 63, w = tid >> 6;
  const int l16 = lane & 15, lg = lane >> 4;
  const int qg = w >> 1, kg = w & 1;
  const int wgp = (blockIdx.x & 7) * 128 + (blockIdx.x >> 3);  // 1024 = 8*128
  const int bh = wgp >> 5;
  const int b = bh >> 4, h = bh & 15;
  const int q0 = (wgp & 31) * 64;
  const int qw0 = q0 + qg * 16;
  const size_t kvb = (size_t)bh * SEQ * DKH;

  bf16x8 aq[2];
#pragma unroll
  for (int kc = 0; kc < 2; ++kc)
    aq[kc] = *(const bf16x8*)&Qp[kvb + (size_t)(qw0 + l16) * DKH + kc * 32 + lg * 8];

  f32x4 o[4];
#pragma unroll
  for (int dt = 0; dt < 4; ++dt) o[dt] = (f32x4){0.f, 0.f, 0.f, 0.f};
  f32x4 lacc = (f32x4){0.f, 0.f, 0.f, 0.f};

  bf16x8 ones;
#pragma unroll
  for (int j = 0; j < 8; ++j) ones[j] = (bf16)1.0f;

  // staging (pre-swizzled source, linear dest tid*16B):
  const int kr = tid >> 3, oct = tid & 7;       // K: row kr in [0,64), chunk oct
  const bf16* gKs = Kp + kvb + (size_t)kr * DKH + (oct ^ (kr & 7)) * 8;
  const bf16* gVs = Vt + kvb + (size_t)kr * SEQ + (oct ^ (kr & 7)) * 8;  // V: row d=kr
  // P: per-qg region [16 q][64 k] @ 128B rows; this wave owns chunks kg*4..kg*4+3
  bf16* lPq = &lP[qg * 1024];
  int pwr[2];
#pragma unroll
  for (int fn = 0; fn < 2; ++fn)
    pwr[fn] = l16 * 64 + (((kg * 4 + fn * 2 + (lg >> 1)) ^ (l16 & 7)) << 3) +
              ((lg & 1) << 2);
  const int prd = l16 * 64 + (((kg * 4 + lg) ^ (l16 & 7)) << 3);

  auto stageTile = [&](bf16* dK, bf16* dV, int t) {
    const size_t ko = (size_t)t * 64 * DKH;
    const int vo = t * 64;
    GLL16(gKs + ko, dK + tid * 8);
    GLL16(gVs + vo, dV + tid * 8);
  };

  auto computeTile = [&](const bf16* K, const bf16* V) {
    // S^T: st[fn][r] = S[q=qw0+l16][k = kg*32 + fn*16 + lg*4 + r] (log2 units)
    f32x4 st[2];
    __builtin_amdgcn_s_setprio(1);
#pragma unroll
    for (int fn = 0; fn < 2; ++fn) {
      const int row = kg * 32 + fn * 16 + l16;
      bf16x8 ka = *(const bf16x8*)&K[row * 64 + ((lg ^ (row & 7)) << 3)];
      bf16x8 kb = *(const bf16x8*)&K[row * 64 + (((4 + lg) ^ (row & 7)) << 3)];
      f32x4 tt = (f32x4){0.f, 0.f, 0.f, 0.f};
      tt = mfma16(ka, aq[0], tt);
      tt = mfma16(kb, aq[1], tt);
      st[fn] = tt;
    }
    __builtin_amdgcn_s_setprio(0);

    // P = exp2(S - MSHIFT) -> shared per-qg LDS (A-frag layout, own chunks)
#pragma unroll
    for (int fn = 0; fn < 2; ++fn) {
      uint2 pw;
      pw.x = pk2(fexp2(st[fn][0] - MSHIFT), fexp2(st[fn][1] - MSHIFT));
      pw.y = pk2(fexp2(st[fn][2] - MSHIFT), fexp2(st[fn][3] - MSHIFT));
      *(uint2*)&lPq[pwr[fn]] = pw;
    }
    bf16x8 pa = *(const bf16x8*)&lPq[prd];

    __builtin_amdgcn_s_setprio(1);
    lacc = mfma16(pa, ones, lacc);
#pragma unroll
    for (int dt = 0; dt < 4; ++dt) {
      const int n = dt * 16 + l16;
      bf16x8 vv = *(const bf16x8*)&V[n * 64 + (((kg * 4 + lg) ^ (n & 7)) << 3)];
      o[dt] = mfma16(pa, vv, o[dt]);
    }
    __builtin_amdgcn_s_setprio(0);
  };

  stageTile(lK0, lV0, 0);
  __syncthreads();

  const int NT = SEQ / 64;  // 32 (even)
  for (int t = 0; t < NT; t += 2) {
    if (t + 1 < NT) stageTile(lK1, lV1, t + 1);
    computeTile(lK0, lV0);
    __syncthreads();
    if (t + 2 < NT) stageTile(lK0, lV0, t + 2);
    computeTile(lK1, lV1);
    __syncthreads();
  }

  // ---- combine the two k-halves (partials additive: static shift) ----
  // qg0->lK0, qg1->lV0, qg2->lK1, qg3->lV1 (all dead); l in lP.
  float* cmb = (qg == 0) ? (float*)lK0 : (qg == 1) ? (float*)lV0
             : (qg == 2) ? (float*)lK1 : (float*)lV1;
  float* cl = (float*)lP;
  if (kg == 1) {
#pragma unroll
    for (int dt = 0; dt < 4; ++dt)
      *(f32x4*)&cmb[(dt * 16 + l16) * 16 + lg * 4] = o[dt];
    if (l16 == 0) {
#pragma unroll
      for (int r = 0; r < 4; ++r)
        cl[qg * 16 + lg * 4 + r] = lacc[r];
    }
  }
  __syncthreads();
  if (kg == 0) {
#pragma unroll
    for (int dt = 0; dt < 4; ++dt) {
      f32x4 p = *(const f32x4*)&cmb[(dt * 16 + l16) * 16 + lg * 4];
      o[dt][0] += p[0]; o[dt][1] += p[1];
      o[dt][2] += p[2]; o[dt][3] += p[3];
    }
    float linv[4];
#pragma unroll
    for (int r = 0; r < 4; ++r)
      linv[r] = 1.f / (lacc[r] + cl[qg * 16 + lg * 4 + r]);
#pragma unroll
    for (int r = 0; r < 4; ++r) {
      const int q = qw0 + lg * 4 + r;
#pragma unroll
      for (int dt = 0; dt < 4; ++dt) {
        const int d = dt * 16 + l16;
        Op[((size_t)(b * SEQ + q)) * D_MODEL + h * DKH + d] =
            (bf16)(o[dt][r] * linv[r]);
      }
    }
  }
}

// ---------------------------------------------------------------------------
extern "C" void kernel_launch(void* const* d_in, const int* in_sizes, int n_in,
                              void* d_out, int out_size, void* d_ws, size_t ws_size,
                              hipStream_t stream) {
  (void)in_sizes; (void)n_in; (void)out_size; (void)ws_size;
  const float* query = (const float*)d_in[0];
  const float* key   = (const float*)d_in[1];
  const float* value = (const float*)d_in[2];
  const float* Wq    = (const float*)d_in[3];
  const float* bq    = (const float*)d_in[4];
  const float* Wk    = (const float*)d_in[5];
  const float* bk    = (const float*)d_in[6];
  const float* Wv    = (const float*)d_in[7];
  const float* bv    = (const float*)d_in[8];
  const float* Wo    = (const float*)d_in[9];
  const float* bo    = (const float*)d_in[10];
  const float* theta = (const float*)d_in[11];
  const float* gate  = (const float*)d_in[12];

  float* bqp = (float*)d_ws;       // 1024 floats (transformed bq)
  bf16* wb = (bf16*)((char*)d_ws + 8192);
  bf16* Xq  = wb;                  // 4096x1024 bf16
  bf16* Xk  = Xq + 4194304;
  bf16* Xv  = Xk + 4194304;
  bf16* Wqp = Xv + 4194304;        // 1024x1024 bf16 (transformed)
  bf16* Wkp = Wqp + 1048576;
  bf16* Wvp = Wkp + 1048576;
  bf16* Wop = Wvp + 1048576;
  bf16* Qp  = Wop + 1048576;       // [B,H,S,64] bf16
  bf16* Kp  = Qp + 4194304;
  bf16* Vt  = Kp + 4194304;        // [B,H,64,S] bf16 (V transposed)
  bf16* Op  = Vt + 4194304;        // [B,S,1024] bf16

  prep<<<16384, 256, 0, stream>>>(query, key, value, Wq, bq, Wk, Wv, Wo,
                                  gate, theta, Xq, Xk, Xv,
                                  Wqp, Wkp, Wvp, Wop, bqp);
  gemm_qkv<<<768, 256, 0, stream>>>(Xq, Xk, Xv, Wqp, Wkp, Wvp,
                                    bqp, bk, bv, Qp, Kp, Vt);
  attn_kernel<<<1024, 512, 0, stream>>>(Qp, Kp, Vt, Op);
  gemm_out_k<<<256, 256, 0, stream>>>(Op, Wop, bo, (float*)d_out);
}

// Round 18
// 120.980 us; speedup vs baseline: 1.1433x; 1.0669x over previous
//
#include <hip/hip_runtime.h>

// QuantumGateAttention — reduced to standard MHA with transformed Wq'
// (rotation-blend + 1/sqrt(dk) + log2(e) folded). bf16 MFMA, fp32 accum.
// FINAL (= v14, measured best 121.3us): attn KVT=128 with GLL16 staging
// (pre-swizzled global source, linear LDS dest), double-buffer as two
// DISTINCT __shared__ objects + 2x-unrolled loop (alias-provable, no vmcnt
// before ds_reads); static-shift softmax (exp2); l via ones-MFMA; 8 waves =
// 4 qg x 2 kg, 128 q/block; LDS combine epilogue. GEMMs: 128x128 BK=64
// GLL16 both operands, XCD-swizzled grids.

typedef __bf16 bf16;
typedef __attribute__((ext_vector_type(8))) bf16 bf16x8;
typedef __attribute__((ext_vector_type(4))) bf16 bf16x4;
typedef __attribute__((ext_vector_type(2))) bf16 bf16x2;
typedef __attribute__((ext_vector_type(4))) float f32x4;
typedef unsigned int u32;

#define D_MODEL 1024
#define NH 16
#define DKH 64
#define SEQ 2048

#define GLL16(g, l) __builtin_amdgcn_global_load_lds(                      \
    (const __attribute__((address_space(1))) void*)(g),                    \
    (__attribute__((address_space(3))) void*)(l), 16, 0, 0)

static __device__ __forceinline__ f32x4 mfma16(bf16x8 a, bf16x8 b, f32x4 c) {
  return __builtin_amdgcn_mfma_f32_16x16x32_bf16(a, b, c, 0, 0, 0);
}

static __device__ __forceinline__ u32 pk2(float a, float b) {
  bf16x2 v; v[0] = (bf16)a; v[1] = (bf16)b;
  return __builtin_bit_cast(u32, v);
}

static __device__ __forceinline__ float fexp2(float x) {
#if __has_builtin(__builtin_amdgcn_exp2f)
  return __builtin_amdgcn_exp2f(x);
#else
  return exp2f(x);
#endif
}

// scale = 1/sqrt(dk) * log2(e)
#define CQK 0.1803368801111244f
// static softmax shift (log2 units)
#define MSHIFT 12.0f

// ---------------------------------------------------------------------------
// prep: id<4096 -> weights (wz=id>>10: 0 Wq'-transform, 1..3 cvt Wk/Wv/Wo);
//       id>=4096 -> input cvt (iz: 0 q, 1 k, 2 v)
// ---------------------------------------------------------------------------
__global__ __launch_bounds__(256) void prep(const float* __restrict__ query,
                                            const float* __restrict__ key,
                                            const float* __restrict__ value,
                                            const float* __restrict__ Wq,
                                            const float* __restrict__ bq,
                                            const float* __restrict__ Wk,
                                            const float* __restrict__ Wv,
                                            const float* __restrict__ Wo,
                                            const float* __restrict__ gate,
                                            const float* __restrict__ theta,
                                            bf16* __restrict__ Xq,
                                            bf16* __restrict__ Xk,
                                            bf16* __restrict__ Xv,
                                            bf16* __restrict__ Wqp,
                                            bf16* __restrict__ Wkp,
                                            bf16* __restrict__ Wvp,
                                            bf16* __restrict__ Wop,
                                            float* __restrict__ bqp) {
  const int id = blockIdx.x;
  const int tid = threadIdx.x;
  if (id >= 4096) {
    const int rem = id - 4096;
    const int iz = rem >> 12;
    const int ib = rem & 4095;
    const float* s = (iz == 0) ? query : (iz == 1) ? key : value;
    bf16* d = (iz == 0) ? Xq : (iz == 1) ? Xk : Xv;
    const size_t i = (size_t)(ib * 256 + tid) * 4;
    float4 w = *(const float4*)(s + i);
    bf16x4 o; o[0] = (bf16)w.x; o[1] = (bf16)w.y; o[2] = (bf16)w.z; o[3] = (bf16)w.w;
    *(bf16x4*)(d + i) = o;
    return;
  }
  const int wz = id >> 10, wb = id & 1023;
  if (wz != 0) {
    const float* s = (wz == 1) ? Wk : (wz == 2) ? Wv : Wo;
    bf16* dd = (wz == 1) ? Wkp : (wz == 2) ? Wvp : Wop;
    const size_t i = (size_t)(wb * 256 + tid) * 4;
    float4 v = *(const float4*)(s + i);
    bf16x4 o4; o4[0] = (bf16)v.x; o4[1] = (bf16)v.y; o4[2] = (bf16)v.z; o4[3] = (bf16)v.w;
    *(bf16x4*)(dd + i) = o4;
    return;
  }
  __shared__ float red[4];
  float ssum = 0.f;
  for (int i = tid; i < D_MODEL; i += 256) ssum += gate[i];
#pragma unroll
  for (int off = 32; off > 0; off >>= 1) ssum += __shfl_down(ssum, off);
  if ((tid & 63) == 0) red[tid >> 6] = ssum;
  __syncthreads();
  const float g = 1.f / (1.f + __expf(-(red[0] + red[1] + red[2] + red[3]) / 1024.f));

  const int t = wb * 256 + tid;
  const int r = t >> 8;
  const int c0 = (t & 255) * 4;
  const int d = r & 63, h = r >> 6;
  float4 w = *(const float4*)(Wq + (size_t)r * D_MODEL + c0);
  float4 o;
  if (d == 0) {
    const float a = (g * cosf(theta[h]) + (1.f - g)) * CQK;
    const float bb = (g * sinf(theta[h])) * CQK;
    float4 w2 = *(const float4*)(Wq + (size_t)(r + 1) * D_MODEL + c0);
    o.x = a * w.x - bb * w2.x; o.y = a * w.y - bb * w2.y;
    o.z = a * w.z - bb * w2.z; o.w = a * w.w - bb * w2.w;
    if (c0 == 0) bqp[r] = a * bq[r] - bb * bq[r + 1];
  } else if (d == 1) {
    const float a = (g * cosf(theta[h]) + (1.f - g)) * CQK;
    const float bb = (g * sinf(theta[h])) * CQK;
    float4 w2 = *(const float4*)(Wq + (size_t)(r - 1) * D_MODEL + c0);
    o.x = bb * w2.x + a * w.x; o.y = bb * w2.y + a * w.y;
    o.z = bb * w2.z + a * w.z; o.w = bb * w2.w + a * w.w;
    if (c0 == 0) bqp[r] = bb * bq[r - 1] + a * bq[r];
  } else {
    o.x = CQK * w.x; o.y = CQK * w.y;
    o.z = CQK * w.z; o.w = CQK * w.w;
    if (c0 == 0) bqp[r] = CQK * bq[r];
  }
  bf16x4 ov; ov[0] = (bf16)o.x; ov[1] = (bf16)o.y; ov[2] = (bf16)o.z; ov[3] = (bf16)o.w;
  *(bf16x4*)(Wqp + (size_t)r * D_MODEL + c0) = ov;
}

// ---------------------------------------------------------------------------
// GEMM main loop: C(128x128) = A * Bt^T, BK=64, GLL16 staging with oct^row
// swizzle (pre-swizzled global source, linear LDS dest).
// ---------------------------------------------------------------------------
static __device__ __forceinline__ void gemm_bt_main(const bf16* __restrict__ A,
                                                    const bf16* __restrict__ Bt,
                                                    int tm, int tn, int K,
                                                    f32x4 acc[4][4]) {
  __shared__ bf16 lA[8192];  // [128][64], chunk oct ^= (row&7)
  __shared__ bf16 lB[8192];
  const int tid = threadIdx.x;
  const int lane = tid & 63, wv = tid >> 6;
  const int wm = wv >> 1, wn = wv & 1;
  const int l16 = lane & 15, lg = lane >> 4;

#pragma unroll
  for (int i = 0; i < 4; ++i)
#pragma unroll
    for (int j = 0; j < 4; ++j) acc[i][j] = (f32x4){0.f, 0.f, 0.f, 0.f};

  int offA[4][2], offB[4][2];
#pragma unroll
  for (int f = 0; f < 4; ++f)
#pragma unroll
    for (int kc = 0; kc < 2; ++kc) {
      const int m = wm * 64 + f * 16 + l16;
      offA[f][kc] = m * 64 + (((kc * 4 + lg) ^ (m & 7)) << 3);
      const int n = wn * 64 + f * 16 + l16;
      offB[f][kc] = n * 64 + (((kc * 4 + lg) ^ (n & 7)) << 3);
    }

  const int rowb = tid >> 3, oct = tid & 7;
  const int soct = oct ^ (rowb & 7);
  const bf16* gA[4];
  const bf16* gB[4];
#pragma unroll
  for (int rd = 0; rd < 4; ++rd) {
    gA[rd] = A + (size_t)(tm + rd * 32 + rowb) * K + soct * 8;
    gB[rd] = Bt + (size_t)(tn + rd * 32 + rowb) * K + soct * 8;
  }

  for (int kt = 0; kt < K; kt += 64) {
    __syncthreads();
#pragma unroll
    for (int rd = 0; rd < 4; ++rd) {
      GLL16(gA[rd] + kt, &lA[rd * 2048 + wv * 512]);
      GLL16(gB[rd] + kt, &lB[rd * 2048 + wv * 512]);
    }
    __syncthreads();
#pragma unroll
    for (int kc = 0; kc < 2; ++kc) {
      bf16x8 af[4], bv[4];
#pragma unroll
      for (int f = 0; f < 4; ++f) {
        af[f] = *(const bf16x8*)&lA[offA[f][kc]];
        bv[f] = *(const bf16x8*)&lB[offB[f][kc]];
      }
#pragma unroll
      for (int i = 0; i < 4; ++i)
#pragma unroll
        for (int j = 0; j < 4; ++j)
          acc[i][j] = mfma16(af[i], bv[j], acc[i][j]);
    }
  }
}

// QKV projections (1D grid 768, XCD-swizzled): z=0 Q', z=1 K -> [B,H,S,64];
// z=2 V -> Vt [B,H,64,S].
__global__ __launch_bounds__(256) void gemm_qkv(
    const bf16* __restrict__ Xq, const bf16* __restrict__ Xk, const bf16* __restrict__ Xv,
    const bf16* __restrict__ Wq, const bf16* __restrict__ Wk, const bf16* __restrict__ Wv,
    const float* __restrict__ bqp, const float* __restrict__ bk, const float* __restrict__ bv,
    bf16* __restrict__ Qp, bf16* __restrict__ Kp, bf16* __restrict__ Vt) {
  const int wgp = (blockIdx.x & 7) * 96 + (blockIdx.x >> 3);  // 768 = 8*96
  const int z = wgp >> 8;
  const int rem = wgp & 255;
  const int tm = (rem >> 3) * 128, tn = (rem & 7) * 128;
  const bf16* A = (z == 0) ? Xq : (z == 1) ? Xk : Xv;
  const bf16* Bt = (z == 0) ? Wq : (z == 1) ? Wk : Wv;
  const float* bias = (z == 0) ? bqp : (z == 1) ? bk : bv;
  f32x4 acc[4][4];
  gemm_bt_main(A, Bt, tm, tn, D_MODEL, acc);
  const int lane = threadIdx.x & 63, wv = threadIdx.x >> 6;
  const int wm = wv >> 1, wn = wv & 1, l16 = lane & 15, lg = lane >> 4;
  if (z < 2) {
    bf16* C = (z == 0) ? Qp : Kp;
#pragma unroll
    for (int i = 0; i < 4; ++i) {
      const int m0 = tm + wm * 64 + i * 16 + lg * 4;
#pragma unroll
      for (int j = 0; j < 4; ++j) {
        const int n = tn + wn * 64 + j * 16 + l16;
        const float bb = bias[n];
        const int h = n >> 6, d = n & 63;
#pragma unroll
        for (int r = 0; r < 4; ++r) {
          const int m = m0 + r;
          const int b = m >> 11, s = m & 2047;
          C[((size_t)(b * NH + h) * SEQ + s) * DKH + d] = (bf16)(acc[i][j][r] + bb);
        }
      }
    }
  } else {
#pragma unroll
    for (int i = 0; i < 4; ++i) {
      const int m0 = tm + wm * 64 + i * 16 + lg * 4;
      const int b = m0 >> 11, s0 = m0 & 2047;
#pragma unroll
      for (int j = 0; j < 4; ++j) {
        const int n = tn + wn * 64 + j * 16 + l16;
        const float bb = bias[n];
        const int h = n >> 6, d = n & 63;
        bf16x4 ov;
#pragma unroll
        for (int r = 0; r < 4; ++r) ov[r] = (bf16)(acc[i][j][r] + bb);
        *(bf16x4*)&Vt[((size_t)(b * NH + h) * DKH + d) * SEQ + s0] = ov;
      }
    }
  }
}

// final projection (1D grid 256, XCD-swizzled): d_out = O @ Wo^T + bo, fp32
__global__ __launch_bounds__(256) void gemm_out_k(const bf16* __restrict__ A,
                                                  const bf16* __restrict__ Bt,
                                                  const float* __restrict__ bias,
                                                  float* __restrict__ C) {
  const int wgp = (blockIdx.x & 7) * 32 + (blockIdx.x >> 3);  // 256 = 8*32
  const int tm = (wgp >> 3) * 128, tn = (wgp & 7) * 128;
  f32x4 acc[4][4];
  gemm_bt_main(A, Bt, tm, tn, D_MODEL, acc);
  const int lane = threadIdx.x & 63, wv = threadIdx.x >> 6;
  const int wm = wv >> 1, wn = wv & 1, l16 = lane & 15, lg = lane >> 4;
#pragma unroll
  for (int i = 0; i < 4; ++i) {
    const int m0 = tm + wm * 64 + i * 16 + lg * 4;
#pragma unroll
    for (int j = 0; j < 4; ++j) {
      const int n = tn + wn * 64 + j * 16 + l16;
      const float bb = bias[n];
#pragma unroll
      for (int r = 0; r < 4; ++r)
        C[(size_t)(m0 + r) * D_MODEL + n] = acc[i][j][r] + bb;
    }
  }
}

// ---------------------------------------------------------------------------
// Flash attention (v14, measured best): KVT=128, GLL16 staging (pre-swizzled
// global source, linear LDS dest), double buffer = two DISTINCT __shared__
// objects with a 2x-unrolled loop. 8 waves = 4 qg x 2 kg; 128 q/block;
// static-shift softmax; P per-wave [16q][2qq][32k] @128B rows; l via
// ones-MFMA; LDS combine epilogue. Grid 512 XCD-swizzled.
// ---------------------------------------------------------------------------
__global__ __launch_bounds__(512, 4) void attn_kernel(const bf16* __restrict__ Qp,
                                                      const bf16* __restrict__ Kp,
                                                      const bf16* __restrict__ Vt,
                                                      bf16* __restrict__ Op) {
  __shared__ __align__(16) bf16 lK0[8192];  // [128 k][64 d], content oct^(kr&7)
  __shared__ __align__(16) bf16 lV0[8192];  // [64 d][128 k], content c^(d&7)
  __shared__ __align__(16) bf16 lK1[8192];
  __shared__ __align__(16) bf16 lV1[8192];
  __shared__ __align__(16) bf16 lP[8192];   // 8 waves x 1024

  const int tid = threadIdx.x;
  const int lane = tid & 63, w = tid >> 6;
  const int l16 = lane & 15, lg = lane >> 4;
  const int qg = w >> 1, kg = w & 1;
  const int wgp = (blockIdx.x & 7) * 64 + (blockIdx.x >> 3);  // 512 = 8*64
  const int bh = wgp >> 4;
  const int b = bh >> 4, h = bh & 15;
  const int q0 = (wgp & 15) * 128;
  const int qw0 = q0 + qg * 32;
  const size_t kvb = (size_t)bh * SEQ * DKH;

  bf16x8 aq[2][2];
#pragma unroll
  for (int qq = 0; qq < 2; ++qq)
#pragma unroll
    for (int kc = 0; kc < 2; ++kc)
      aq[qq][kc] = *(const bf16x8*)&Qp[kvb +
          (size_t)(qw0 + qq * 16 + l16) * DKH + kc * 32 + lg * 8];

  f32x4 o[2][4];
#pragma unroll
  for (int qq = 0; qq < 2; ++qq)
#pragma unroll
    for (int dt = 0; dt < 4; ++dt) o[qq][dt] = (f32x4){0.f, 0.f, 0.f, 0.f};
  f32x4 lacc[2];
  lacc[0] = (f32x4){0.f, 0.f, 0.f, 0.f};
  lacc[1] = (f32x4){0.f, 0.f, 0.f, 0.f};

  bf16x8 ones;
#pragma unroll
  for (int j = 0; j < 8; ++j) ones[j] = (bf16)1.0f;

  // staging sources (PRE-SWIZZLED in global so LDS dest is linear tid*16B):
  const int kr = tid >> 3, oct = tid & 7;
  const bf16* gKs = Kp + kvb + (size_t)kr * DKH + (oct ^ (kr & 7)) * 8;
  const bf16* gKs2 = gKs + (size_t)64 * DKH;
  const int vd = tid >> 4, vsc = tid & 15;
  const bf16* gVs = Vt + kvb + (size_t)vd * SEQ + ((vsc ^ (vd & 7)) * 8);
  const bf16* gVs2 = gVs + (size_t)32 * SEQ;

  // P addresses: per-wave [16 q][qq(2)][32 k], 128B rows (bank-balanced)
  bf16* lPw = &lP[w * 1024];
  int pwr[2][2];
#pragma unroll
  for (int fn = 0; fn < 2; ++fn)
#pragma unroll
    for (int qq = 0; qq < 2; ++qq)
      pwr[fn][qq] = l16 * 64 + (((qq * 4 + fn * 2 + (lg >> 1)) ^ (l16 & 7)) << 3) +
                    ((lg & 1) << 2);
  int prd[2];
#pragma unroll
  for (int qq = 0; qq < 2; ++qq)
    prd[qq] = l16 * 64 + (((qq * 4 + lg) ^ (l16 & 7)) << 3);

  auto stageTile = [&](bf16* dK, bf16* dV, int t) {
    const size_t ko = (size_t)t * 128 * DKH;
    const int vo = t * 128;
    GLL16(gKs + ko, dK + tid * 8);
    GLL16(gKs2 + ko, dK + tid * 8 + 4096);
    GLL16(gVs + vo, dV + tid * 8);
    GLL16(gVs2 + vo, dV + tid * 8 + 4096);
  };

  auto computeTile = [&](const bf16* K, const bf16* V) {
#pragma unroll
    for (int ss = 0; ss < 2; ++ss) {
      f32x4 st[2][2];
      __builtin_amdgcn_s_setprio(1);
#pragma unroll
      for (int fn = 0; fn < 2; ++fn) {
        const int row = ss * 64 + kg * 32 + fn * 16 + l16;
        bf16x8 ka = *(const bf16x8*)&K[row * 64 + ((lg ^ (row & 7)) << 3)];
        bf16x8 kb = *(const bf16x8*)&K[row * 64 + (((4 + lg) ^ (row & 7)) << 3)];
#pragma unroll
        for (int qq = 0; qq < 2; ++qq) {
          f32x4 tt = (f32x4){0.f, 0.f, 0.f, 0.f};
          tt = mfma16(ka, aq[qq][0], tt);
          tt = mfma16(kb, aq[qq][1], tt);
          st[fn][qq] = tt;
        }
      }
      __builtin_amdgcn_s_setprio(0);

#pragma unroll
      for (int fn = 0; fn < 2; ++fn)
#pragma unroll
        for (int qq = 0; qq < 2; ++qq) {
          uint2 pw;
          pw.x = pk2(fexp2(st[fn][qq][0] - MSHIFT), fexp2(st[fn][qq][1] - MSHIFT));
          pw.y = pk2(fexp2(st[fn][qq][2] - MSHIFT), fexp2(st[fn][qq][3] - MSHIFT));
          *(uint2*)&lPw[pwr[fn][qq]] = pw;
        }

      bf16x8 pa0 = *(const bf16x8*)&lPw[prd[0]];
      bf16x8 pa1 = *(const bf16x8*)&lPw[prd[1]];

      __builtin_amdgcn_s_setprio(1);
      lacc[0] = mfma16(pa0, ones, lacc[0]);
      lacc[1] = mfma16(pa1, ones, lacc[1]);
#pragma unroll
      for (int dt = 0; dt < 4; ++dt) {
        const int n = dt * 16 + l16;
        bf16x8 vv = *(const bf16x8*)&V[n * 128 +
                                      (((ss * 8 + kg * 4 + lg) ^ (n & 7)) << 3)];
        o[0][dt] = mfma16(pa0, vv, o[0][dt]);
        o[1][dt] = mfma16(pa1, vv, o[1][dt]);
      }
      __builtin_amdgcn_s_setprio(0);
    }
  };

  // prologue: tile 0 -> buf0
  stageTile(lK0, lV0, 0);
  __syncthreads();

  const int NT = SEQ / 128;  // 16 (even)
  for (int t = 0; t < NT; t += 2) {
    if (t + 1 < NT) stageTile(lK1, lV1, t + 1);
    computeTile(lK0, lV0);
    __syncthreads();
    if (t + 2 < NT) stageTile(lK0, lV0, t + 2);
    computeTile(lK1, lV1);
    __syncthreads();
  }

  // ---- combine the two k-halves (partials additive: static shift) ----
  float* cmb0 = (float*)lK0;
  float* cmb1 = (float*)lK1;
  float* cl = (float*)lP;
  float* cmb = (qg < 2) ? (cmb0 + (size_t)qg * 2048) : (cmb1 + (size_t)(qg - 2) * 2048);
  if (kg == 1) {
#pragma unroll
    for (int qq = 0; qq < 2; ++qq)
#pragma unroll
      for (int dt = 0; dt < 4; ++dt)
        *(f32x4*)&cmb[((qq * 4 + dt) * 16 + l16) * 16 + lg * 4] = o[qq][dt];
    if (l16 == 0) {
#pragma unroll
      for (int qq = 0; qq < 2; ++qq)
#pragma unroll
        for (int r = 0; r < 4; ++r)
          cl[(qg * 2 + qq) * 16 + lg * 4 + r] = lacc[qq][r];
    }
  }
  __syncthreads();
  if (kg == 0) {
#pragma unroll
    for (int qq = 0; qq < 2; ++qq) {
#pragma unroll
      for (int dt = 0; dt < 4; ++dt) {
        f32x4 p = *(const f32x4*)&cmb[((qq * 4 + dt) * 16 + l16) * 16 + lg * 4];
        o[qq][dt][0] += p[0]; o[qq][dt][1] += p[1];
        o[qq][dt][2] += p[2]; o[qq][dt][3] += p[3];
      }
      float linv[4];
#pragma unroll
      for (int r = 0; r < 4; ++r)
        linv[r] = 1.f / (lacc[qq][r] + cl[(qg * 2 + qq) * 16 + lg * 4 + r]);
#pragma unroll
      for (int r = 0; r < 4; ++r) {
        const int q = qw0 + qq * 16 + lg * 4 + r;
#pragma unroll
        for (int dt = 0; dt < 4; ++dt) {
          const int d = dt * 16 + l16;
          Op[((size_t)(b * SEQ + q)) * D_MODEL + h * DKH + d] =
              (bf16)(o[qq][dt][r] * linv[r]);
        }
      }
    }
  }
}

// ---------------------------------------------------------------------------
extern "C" void kernel_launch(void* const* d_in, const int* in_sizes, int n_in,
                              void* d_out, int out_size, void* d_ws, size_t ws_size,
                              hipStream_t stream) {
  (void)in_sizes; (void)n_in; (void)out_size; (void)ws_size;
  const float* query = (const float*)d_in[0];
  const float* key   = (const float*)d_in[1];
  const float* value = (const float*)d_in[2];
  const float* Wq    = (const float*)d_in[3];
  const float* bq    = (const float*)d_in[4];
  const float* Wk    = (const float*)d_in[5];
  const float* bk    = (const float*)d_in[6];
  const float* Wv    = (const float*)d_in[7];
  const float* bv    = (const float*)d_in[8];
  const float* Wo    = (const float*)d_in[9];
  const float* bo    = (const float*)d_in[10];
  const float* theta = (const float*)d_in[11];
  const float* gate  = (const float*)d_in[12];

  float* bqp = (float*)d_ws;       // 1024 floats (transformed bq)
  bf16* wb = (bf16*)((char*)d_ws + 8192);
  bf16* Xq  = wb;                  // 4096x1024 bf16
  bf16* Xk  = Xq + 4194304;
  bf16* Xv  = Xk + 4194304;
  bf16* Wqp = Xv + 4194304;        // 1024x1024 bf16 (transformed)
  bf16* Wkp = Wqp + 1048576;
  bf16* Wvp = Wkp + 1048576;
  bf16* Wop = Wvp + 1048576;
  bf16* Qp  = Wop + 1048576;       // [B,H,S,64] bf16
  bf16* Kp  = Qp + 4194304;
  bf16* Vt  = Kp + 4194304;        // [B,H,64,S] bf16 (V transposed)
  bf16* Op  = Vt + 4194304;        // [B,S,1024] bf16

  prep<<<16384, 256, 0, stream>>>(query, key, value, Wq, bq, Wk, Wv, Wo,
                                  gate, theta, Xq, Xk, Xv,
                                  Wqp, Wkp, Wvp, Wop, bqp);
  gemm_qkv<<<768, 256, 0, stream>>>(Xq, Xk, Xv, Wqp, Wkp, Wvp,
                                    bqp, bk, bv, Qp, Kp, Vt);
  attn_kernel<<<512, 512, 0, stream>>>(Qp, Kp, Vt, Op);
  gemm_out_k<<<256, 256, 0, stream>>>(Op, Wop, bo, (float*)d_out);
}